// Round 3
// baseline (130.995 us; speedup 1.0000x reference)
//
#include <hip/hip_runtime.h>
#include <math.h>

// Problem constants
#define BATCH 2
#define NTOK  2048
#define FIN   256
#define HEADS 8
#define FOUT  32
#define BH    (BATCH*HEADS)    // 16
#define NCOL  (HEADS*FOUT)     // 256
#define ROWS  (BATCH*NTOK)     // 4096

typedef _Float16 f16;
typedef _Float16 f16x8 __attribute__((ext_vector_type(8)));
typedef float    f32x4 __attribute__((ext_vector_type(4)));

// ---------------------------------------------------------------------------
// Workspace layout (float offsets).
// V1/P2V fg-plane-major [bh][fg][2049][4]. f16 hi/lo split operands for K1.
// ---------------------------------------------------------------------------
static const size_t OFF_E1   = 1048576;                 // e1  [16][2048]
static const size_t OFF_E2   = OFF_E1 + 32768;          // e2  [16][2048]
static const size_t OFF_SKEY = OFF_E2 + 32768;          // skey[16][2048]
static const size_t OFF_SIDX = OFF_SKEY + 32768;        // sidx[16][2048] int
static const size_t OFF_W1S  = OFF_SIDX + 32768;        // w1s [16][2048]
static const size_t OFF_W2S  = OFF_W1S + 32768;         // w2s [16][2048]
static const size_t OFF_S1   = OFF_W2S + 32768;         // S1  [16][2049]
static const size_t OFF_P2   = OFF_S1 + 32784;          // P2  [16][2049]
static const size_t OFF_V1   = OFF_P2 + 32784;          // V1  [16][8][2049][4]
static const size_t OFF_P2V  = OFF_V1 + 16u*2049u*32u;  // P2V [16][8][2049][4]
static const size_t OFF_HHI  = OFF_P2V + 16u*2049u*32u; // h_hi [4096][256] f16 (x16 scale)
static const size_t OFF_HLO  = OFF_HHI + 524288;        // h_lo [4096][256] f16
static const size_t OFF_WTHI = OFF_HLO + 524288;        // Wt_hi[256 col][256 k] f16 (x4096 scale)
static const size_t OFF_WTLO = OFF_WTHI + 32768;        // Wt_lo[256][256] f16

// ---------------------------------------------------------------------------
// K0: split h -> (h_hi,h_lo) f16 (scaled x16, row-major [row][k]) and
//     W -> (Wt_hi,Wt_lo) f16 (scaled x4096, TRANSPOSED [col][k]).
// Scaling keeps the lo residuals in f16 normal range (lo ~ ulp/2 of hi).
// grid 528 = 512 h-blocks + 16 W-blocks, block 256.
// ---------------------------------------------------------------------------
__global__ __launch_bounds__(256) void k_split(const float* __restrict__ h,
                                               const float* __restrict__ W,
                                               f16* __restrict__ hhi, f16* __restrict__ hlo,
                                               f16* __restrict__ wthi, f16* __restrict__ wtlo) {
    const int tid = threadIdx.x;
    if (blockIdx.x < 512) {
        const size_t base = ((size_t)blockIdx.x * 256 + tid) * 8;
        const float4 v0 = *(const float4*)(h + base);
        const float4 v1 = *(const float4*)(h + base + 4);
        const float xs[8] = {v0.x,v0.y,v0.z,v0.w,v1.x,v1.y,v1.z,v1.w};
        f16x8 hi8, lo8;
        #pragma unroll
        for (int i = 0; i < 8; ++i) {
            float xv = xs[i] * 16.0f;
            f16 hv = (f16)xv;
            hi8[i] = hv;
            lo8[i] = (f16)(xv - (float)hv);
        }
        *(f16x8*)(hhi + base) = hi8;
        *(f16x8*)(hlo + base) = lo8;
    } else {
        const int k0 = (blockIdx.x - 512) * 16;
        const int c  = tid;
        f16x8 hiA, loA, hiB, loB;
        #pragma unroll
        for (int j = 0; j < 8; ++j) {
            float xv = W[(size_t)(k0 + j) * 256 + c] * 4096.0f;
            f16 hv = (f16)xv;
            hiA[j] = hv; loA[j] = (f16)(xv - (float)hv);
        }
        #pragma unroll
        for (int j = 0; j < 8; ++j) {
            float xv = W[(size_t)(k0 + 8 + j) * 256 + c] * 4096.0f;
            f16 hv = (f16)xv;
            hiB[j] = hv; loB[j] = (f16)(xv - (float)hv);
        }
        f16* pd = wthi + (size_t)c * 256 + k0;
        f16* pe = wtlo + (size_t)c * 256 + k0;
        *(f16x8*)pd = hiA; *(f16x8*)(pd + 8) = hiB;
        *(f16x8*)pe = loA; *(f16x8*)(pe + 8) = loB;
    }
}

// ---------------------------------------------------------------------------
// K1: Wh = h @ W via MFMA f16 hi/lo split (Ah*Bh + Ah*Bl + Al*Bh), fused e12.
// grid 256 blocks x 256 thr; block = 16 rows x 256 cols; wave = 16x64 (4
// 16x16 tiles). Frags loaded straight from L2 (h_hi/Wt_hi are hot, B reused
// 256x), no LDS, no barriers. 2-chunk register pipeline hides L2 latency.
// Frag layout (verified idiom): A row=lane&15, k=(lane>>4)*8+j (k-contig 16B);
// B col=lane&15, same k slice from Wt[col][k]; C col=lane&15, row=(lane>>4)*4+g.
// Epilogue: rescale by 2^-16, write Wh fp32, reduce e1/e2 over 16 lanes.
// ---------------------------------------------------------------------------
__global__ __launch_bounds__(256) void k_mm(const f16* __restrict__ hhi, const f16* __restrict__ hlo,
                                            const f16* __restrict__ wthi, const f16* __restrict__ wtlo,
                                            const float* __restrict__ a,
                                            float* __restrict__ Wh,
                                            float* __restrict__ e1, float* __restrict__ e2) {
    const int tid  = threadIdx.x;
    const int wv   = tid >> 6;
    const int lane = tid & 63;
    const int r    = lane & 15;
    const int q    = lane >> 4;
    const int row0 = blockIdx.x * 16;
    const int col0 = wv * 64;
    const int koff = q * 8;

    const f16* pa_hi = hhi  + (size_t)(row0 + r) * 256 + koff;
    const f16* pa_lo = hlo  + (size_t)(row0 + r) * 256 + koff;
    const f16* pb_hi = wthi + (size_t)(col0 + r) * 256 + koff;
    const f16* pb_lo = wtlo + (size_t)(col0 + r) * 256 + koff;

    f32x4 acc[4];
    #pragma unroll
    for (int t = 0; t < 4; ++t) acc[t] = (f32x4){0.f,0.f,0.f,0.f};

    struct FR { f16x8 ah, al, bh[4], bl[4]; };
    auto ldfr = [&](int ch) {
        FR f;
        const int o = ch * 32;
        f.ah = *(const f16x8*)(pa_hi + o);
        f.al = *(const f16x8*)(pa_lo + o);
        #pragma unroll
        for (int t = 0; t < 4; ++t) {
            f.bh[t] = *(const f16x8*)(pb_hi + t * (16 * 256) + o);
            f.bl[t] = *(const f16x8*)(pb_lo + t * (16 * 256) + o);
        }
        return f;
    };
    auto dom = [&](const FR& f) {
        #pragma unroll
        for (int t = 0; t < 4; ++t) {
            acc[t] = __builtin_amdgcn_mfma_f32_16x16x32_f16(f.ah, f.bh[t], acc[t], 0, 0, 0);
            acc[t] = __builtin_amdgcn_mfma_f32_16x16x32_f16(f.ah, f.bl[t], acc[t], 0, 0, 0);
            acc[t] = __builtin_amdgcn_mfma_f32_16x16x32_f16(f.al, f.bh[t], acc[t], 0, 0, 0);
        }
    };

    FR fa = ldfr(0);
    FR fb = ldfr(1);
    #pragma unroll
    for (int ch = 0; ch < 8; ch += 2) {
        dom(fa);
        if (ch + 2 < 8) fa = ldfr(ch + 2);
        dom(fb);
        if (ch + 3 < 8) fb = ldfr(ch + 3);
    }

    // undo the 2^4 * 2^12 operand scaling
    const float SC = 1.0f / 65536.0f;
    #pragma unroll
    for (int t = 0; t < 4; ++t) acc[t] *= SC;

    // Wh write (fp32)
    #pragma unroll
    for (int t = 0; t < 4; ++t)
        #pragma unroll
        for (int g = 0; g < 4; ++g)
            Wh[(size_t)(row0 + q * 4 + g) * 256 + col0 + t * 16 + r] = acc[t][g];

    // fused e1/e2: col = col0 + t*16 + r -> head = wv*2 + (t>>1), f = (t&1)*16 + r
    const float av10 = a[r], av11 = a[16 + r], av20 = a[32 + r], av21 = a[48 + r];
    float p1[8], p2[8];
    #pragma unroll
    for (int hp = 0; hp < 2; ++hp)
        #pragma unroll
        for (int g = 0; g < 4; ++g) {
            p1[hp * 4 + g] = acc[2 * hp][g] * av10 + acc[2 * hp + 1][g] * av11;
            p2[hp * 4 + g] = acc[2 * hp][g] * av20 + acc[2 * hp + 1][g] * av21;
        }
    #pragma unroll
    for (int m = 1; m < 16; m <<= 1) {
        #pragma unroll
        for (int i = 0; i < 8; ++i) {
            p1[i] += __shfl_xor(p1[i], m, 64);
            p2[i] += __shfl_xor(p2[i], m, 64);
        }
    }
    if (r == 0) {
        #pragma unroll
        for (int hp = 0; hp < 2; ++hp)
            #pragma unroll
            for (int g = 0; g < 4; ++g) {
                const int row  = row0 + q * 4 + g;
                const int b    = row >> 11;
                const int n    = row & (NTOK - 1);
                const int head = wv * 2 + hp;
                e1[(b * HEADS + head) * NTOK + n] = p1[hp * 4 + g];
                e2[(b * HEADS + head) * NTOK + n] = p2[hp * 4 + g];
            }
    }
}

// ---------------------------------------------------------------------------
// Monotone float->u32 bit map packed with (2047-j): one u64 compare gives the
// descending-with-index-tiebreak total order.
// ---------------------------------------------------------------------------
__device__ __forceinline__ unsigned long long sortkey(float f, int j) {
    unsigned int b = __float_as_uint(f);
    unsigned int u = (b & 0x80000000u) ? ~b : (b | 0x80000000u);
    return ((unsigned long long)u << 32) | (unsigned int)(NTOK - 1 - j);
}

// ---------------------------------------------------------------------------
// K3: rank + scatter fused. grid (16 bh, 8 jt), block 512.
// All 2048 keys staged once in LDS (16 KB); thread (jl,half) counts its j
// against one 1024-half (broadcast b128 reads); halves combined in LDS;
// then scatter skey/sidx/exp-weights. Kills the global partial round-trip.
// ---------------------------------------------------------------------------
__global__ __launch_bounds__(512) void k_rank(const float* __restrict__ e2g,
                                              float* __restrict__ skey, int* __restrict__ sidx,
                                              float* __restrict__ w1s, float* __restrict__ w2s) {
    __shared__ unsigned long long keys[NTOK];
    __shared__ int prank[2][256];
    const int tid = threadIdx.x;
    const int bh  = blockIdx.x;
    const int jt  = blockIdx.y;
    #pragma unroll
    for (int qq = 0; qq < 4; ++qq) {
        int idx = qq * 512 + tid;
        keys[idx] = sortkey(e2g[bh * NTOK + idx], idx);
    }
    __syncthreads();
    const int jl = tid & 255;
    const int hf = tid >> 8;
    const int j  = jt * 256 + jl;
    const unsigned long long my = keys[j];
    int rank = 0;
    const ulonglong2* c2 = (const ulonglong2*)(keys + hf * 1024);
    #pragma unroll 8
    for (int qq = 0; qq < 512; ++qq) {
        ulonglong2 v = c2[qq];
        rank += (v.x > my);
        rank += (v.y > my);
    }
    prank[hf][jl] = rank;
    __syncthreads();
    if (tid < 256) {
        const int rk = prank[0][tid] + prank[1][tid];
        const int jj = jt * 256 + tid;
        const float myf = e2g[bh * NTOK + jj];
        skey[bh * NTOK + rk] = myf;
        sidx[bh * NTOK + rk] = jj;
        w1s[bh * NTOK + rk]  = expf(myf);
        w2s[bh * NTOK + rk]  = expf(0.01f * myf);
    }
}

// ---------------------------------------------------------------------------
// K4: work-efficient scans. grid (9 fg, 16 bh, 2 z), block 1024. (unchanged)
// ---------------------------------------------------------------------------
__global__ __launch_bounds__(1024) void k_vscan(const float* __restrict__ Wh,
                                                const int* __restrict__ sidx,
                                                const float* __restrict__ w1s,
                                                const float* __restrict__ w2s,
                                                float* __restrict__ V1,
                                                float* __restrict__ P2V,
                                                float* __restrict__ S1,
                                                float* __restrict__ P2) {
    __shared__ float4 wtot[16];
    __shared__ float4 woff[16];
    const int t    = threadIdx.x;
    const int lane = t & 63;
    const int wv   = t >> 6;
    const int fg   = blockIdx.x;
    const int bh   = blockIdx.y;
    const int z    = blockIdx.z;
    const int b    = bh >> 3;
    const int hh   = bh & 7;
    const float* wsrc = z ? w2s : w1s;

    const int j0 = 2 * t;
    float4 v0, v1;
    if (fg < 8) {
        int sj0 = sidx[bh * NTOK + j0];
        int sj1 = sidx[bh * NTOK + j0 + 1];
        float w0 = wsrc[bh * NTOK + j0];
        float w1 = wsrc[bh * NTOK + j0 + 1];
        float4 g0 = *(const float4*)(Wh + (size_t)(b * NTOK + sj0) * NCOL + hh * FOUT + fg * 4);
        float4 g1 = *(const float4*)(Wh + (size_t)(b * NTOK + sj1) * NCOL + hh * FOUT + fg * 4);
        v0 = make_float4(w0 * g0.x, w0 * g0.y, w0 * g0.z, w0 * g0.w);
        v1 = make_float4(w1 * g1.x, w1 * g1.y, w1 * g1.z, w1 * g1.w);
    } else {
        v0 = make_float4(wsrc[bh * NTOK + j0],     0.f, 0.f, 0.f);
        v1 = make_float4(wsrc[bh * NTOK + j0 + 1], 0.f, 0.f, 0.f);
    }

    float4 s = make_float4(v0.x + v1.x, v0.y + v1.y, v0.z + v1.z, v0.w + v1.w);
    #pragma unroll
    for (int d = 1; d < 64; d <<= 1) {
        float ux = __shfl_up(s.x, (unsigned)d, 64);
        float uy = __shfl_up(s.y, (unsigned)d, 64);
        float uz = __shfl_up(s.z, (unsigned)d, 64);
        float uw = __shfl_up(s.w, (unsigned)d, 64);
        if (lane >= d) { s.x += ux; s.y += uy; s.z += uz; s.w += uw; }
    }
    float4 pair = make_float4(v0.x + v1.x, v0.y + v1.y, v0.z + v1.z, v0.w + v1.w);
    float4 excl = make_float4(s.x - pair.x, s.y - pair.y, s.z - pair.z, s.w - pair.w);
    if (lane == 63) wtot[wv] = s;
    __syncthreads();
    if (t < 16) {
        float4 ws = wtot[t];
        float4 inc = ws;
        #pragma unroll
        for (int d = 1; d < 16; d <<= 1) {
            float ux = __shfl_up(inc.x, (unsigned)d, 16);
            float uy = __shfl_up(inc.y, (unsigned)d, 16);
            float uz = __shfl_up(inc.z, (unsigned)d, 16);
            float uw = __shfl_up(inc.w, (unsigned)d, 16);
            if ((t & 15) >= d) { inc.x += ux; inc.y += uy; inc.z += uz; inc.w += uw; }
        }
        woff[t] = make_float4(inc.x - ws.x, inc.y - ws.y, inc.z - ws.z, inc.w - ws.w);
    }
    __syncthreads();

    float4 base = woff[wv];
    float4 i0 = make_float4(base.x + excl.x + v0.x, base.y + excl.y + v0.y,
                            base.z + excl.z + v0.z, base.w + excl.w + v0.w);
    float4 i1 = make_float4(i0.x + v1.x, i0.y + v1.y, i0.z + v1.z, i0.w + v1.w);

    if (fg < 8) {
        float* dst = z ? P2V : V1;
        float* plane = dst + ((size_t)bh * 8 + fg) * (2049u * 4u);
        *(float4*)(plane + (size_t)(j0 + 1) * 4) = i0;
        *(float4*)(plane + (size_t)(j0 + 2) * 4) = i1;
        if (t == 0)
            *(float4*)plane = make_float4(0.f,0.f,0.f,0.f);
    } else {
        float* dst = z ? P2 : S1;
        dst[bh * 2049 + j0 + 1] = i0.x;
        dst[bh * 2049 + j0 + 2] = i1.x;
        if (t == 0) dst[bh * 2049] = 0.f;
    }
}

// ---------------------------------------------------------------------------
// K5: per (b,h,i): binary-search k_i, combine prefix sums, write output.
// grid (64 itile, 16 bh), block 256 = 32 i x 8 fg  (unchanged)
// ---------------------------------------------------------------------------
__global__ __launch_bounds__(256) void k_out(const float* __restrict__ skey,
                                             const float* __restrict__ e1g,
                                             const float* __restrict__ S1,
                                             const float* __restrict__ P2,
                                             const float* __restrict__ V1,
                                             const float* __restrict__ P2V,
                                             float* __restrict__ out) {
    __shared__ float keys[NTOK];
    const int tid = threadIdx.x;
    const int it  = blockIdx.x;
    const int bh  = blockIdx.y;
    const int b   = bh >> 3;
    const int hh  = bh & 7;
    #pragma unroll
    for (int q = 0; q < 8; ++q)
        keys[q * 256 + tid] = skey[bh * NTOK + q * 256 + tid];
    __syncthreads();

    const int i  = it * 32 + (tid >> 3);
    const int fg = tid & 7;
    const float e1v = e1g[bh * NTOK + i];
    const float th  = -e1v;
    int lo = 0, hi = NTOK;
    while (lo < hi) {
        int mid = (lo + hi) >> 1;
        if (keys[mid] > th) lo = mid + 1; else hi = mid;
    }
    const int k = lo;
    const float A = expf(e1v);
    const float C = expf(0.01f * e1v);
    const float s1  = S1[bh * 2049 + k];
    const float p2k = P2[bh * 2049 + k];
    const float p2t = P2[bh * 2049 + 2048];
    const float l   = A * s1 + C * (p2t - p2k);
    const float inv = 1.0f / l;
    const float* v1p  = V1  + ((size_t)bh * 8 + fg) * (2049u * 4u);
    const float* p2vp = P2V + ((size_t)bh * 8 + fg) * (2049u * 4u);
    float4 v1   = *(const float4*)(v1p  + (size_t)k * 4);
    float4 p2v  = *(const float4*)(p2vp + (size_t)k * 4);
    float4 p2vt = *(const float4*)(p2vp + (size_t)2048 * 4);
    float4 o;
    o.x = (A * v1.x + C * (p2vt.x - p2v.x)) * inv;
    o.y = (A * v1.y + C * (p2vt.y - p2v.y)) * inv;
    o.z = (A * v1.z + C * (p2vt.z - p2v.z)) * inv;
    o.w = (A * v1.w + C * (p2vt.w - p2v.w)) * inv;
    *(float4*)(out + (size_t)(b * NTOK + i) * NCOL + hh * FOUT + fg * 4) = o;
}

// ---------------------------------------------------------------------------
extern "C" void kernel_launch(void* const* d_in, const int* in_sizes, int n_in,
                              void* d_out, int out_size, void* d_ws, size_t ws_size,
                              hipStream_t stream) {
    const float* h = (const float*)d_in[0];
    // d_in[1] = adj — unused by the reference computation
    const float* W = (const float*)d_in[2];
    const float* a = (const float*)d_in[3];
    float* out = (float*)d_out;
    float* ws  = (float*)d_ws;

    float* Wh   = ws;
    float* e1   = ws + OFF_E1;
    float* e2   = ws + OFF_E2;
    float* skey = ws + OFF_SKEY;
    int*   sidx = (int*)(ws + OFF_SIDX);
    float* w1s  = ws + OFF_W1S;
    float* w2s  = ws + OFF_W2S;
    float* S1   = ws + OFF_S1;
    float* P2   = ws + OFF_P2;
    float* V1   = ws + OFF_V1;
    float* P2V  = ws + OFF_P2V;
    f16*   hhi  = (f16*)(ws + OFF_HHI);
    f16*   hlo  = (f16*)(ws + OFF_HLO);
    f16*   wthi = (f16*)(ws + OFF_WTHI);
    f16*   wtlo = (f16*)(ws + OFF_WTLO);

    k_split<<<528,            256, 0, stream>>>(h, W, hhi, hlo, wthi, wtlo);
    k_mm   <<<256,            256, 0, stream>>>(hhi, hlo, wthi, wtlo, a, Wh, e1, e2);
    k_rank <<<dim3(BH, 8),    512, 0, stream>>>(e2, skey, sidx, w1s, w2s);
    k_vscan<<<dim3(9, BH, 2),1024, 0, stream>>>(Wh, sidx, w1s, w2s, V1, P2V, S1, P2);
    k_out  <<<dim3(NTOK/32, BH), 256, 0, stream>>>(skey, e1, S1, P2, V1, P2V, out);
}

// Round 4
// 124.131 us; speedup vs baseline: 1.0553x; 1.0553x over previous
//
#include <hip/hip_runtime.h>
#include <math.h>

// Problem constants
#define BATCH 2
#define NTOK  2048
#define FIN   256
#define HEADS 8
#define FOUT  32
#define BH    (BATCH*HEADS)    // 16
#define NCOL  (HEADS*FOUT)     // 256
#define ROWS  (BATCH*NTOK)     // 4096

typedef _Float16 f16;
typedef _Float16 f16x8 __attribute__((ext_vector_type(8)));
typedef float    f32x4 __attribute__((ext_vector_type(4)));

// ---------------------------------------------------------------------------
// Workspace layout (float offsets).
// V1/P2V fg-plane-major [bh][fg][2049][4]. f16 hi/lo split operands for K1.
// partial ranks alias V1 (rank8 writes partial -> scatter reads -> vscan
// overwrites V1 later; strict stream order makes the aliasing safe).
// ---------------------------------------------------------------------------
static const size_t OFF_E1   = 1048576;                 // e1  [16][2048]
static const size_t OFF_E2   = OFF_E1 + 32768;          // e2  [16][2048]
static const size_t OFF_SKEY = OFF_E2 + 32768;          // skey[16][2048]
static const size_t OFF_SIDX = OFF_SKEY + 32768;        // sidx[16][2048] int
static const size_t OFF_W1S  = OFF_SIDX + 32768;        // w1s [16][2048]
static const size_t OFF_W2S  = OFF_W1S + 32768;         // w2s [16][2048]
static const size_t OFF_S1   = OFF_W2S + 32768;         // S1  [16][2049]
static const size_t OFF_P2   = OFF_S1 + 32784;          // P2  [16][2049]
static const size_t OFF_V1   = OFF_P2 + 32784;          // V1  [16][8][2049][4]
static const size_t OFF_P2V  = OFF_V1 + 16u*2049u*32u;  // P2V [16][8][2049][4]
static const size_t OFF_HHI  = OFF_P2V + 16u*2049u*32u; // h_hi [4096][256] f16 (x16 scale)
static const size_t OFF_HLO  = OFF_HHI + 524288;        // h_lo [4096][256] f16
static const size_t OFF_WTHI = OFF_HLO + 524288;        // Wt_hi[256 col][256 k] f16 (x4096 scale)
static const size_t OFF_WTLO = OFF_WTHI + 32768;        // Wt_lo[256][256] f16
static const size_t OFF_PART = OFF_V1;                  // partial[8][16][2048] int (aliases V1)

// ---------------------------------------------------------------------------
// K0: split h -> (h_hi,h_lo) f16 (scaled x16, row-major [row][k]) and
//     W -> (Wt_hi,Wt_lo) f16 (scaled x4096, TRANSPOSED [col][k]).
// grid 528 = 512 h-blocks + 16 W-blocks, block 256.
// ---------------------------------------------------------------------------
__global__ __launch_bounds__(256) void k_split(const float* __restrict__ h,
                                               const float* __restrict__ W,
                                               f16* __restrict__ hhi, f16* __restrict__ hlo,
                                               f16* __restrict__ wthi, f16* __restrict__ wtlo) {
    const int tid = threadIdx.x;
    if (blockIdx.x < 512) {
        const size_t base = ((size_t)blockIdx.x * 256 + tid) * 8;
        const float4 v0 = *(const float4*)(h + base);
        const float4 v1 = *(const float4*)(h + base + 4);
        const float xs[8] = {v0.x,v0.y,v0.z,v0.w,v1.x,v1.y,v1.z,v1.w};
        f16x8 hi8, lo8;
        #pragma unroll
        for (int i = 0; i < 8; ++i) {
            float xv = xs[i] * 16.0f;
            f16 hv = (f16)xv;
            hi8[i] = hv;
            lo8[i] = (f16)(xv - (float)hv);
        }
        *(f16x8*)(hhi + base) = hi8;
        *(f16x8*)(hlo + base) = lo8;
    } else {
        const int k0 = (blockIdx.x - 512) * 16;
        const int c  = tid;
        f16x8 hiA, loA, hiB, loB;
        #pragma unroll
        for (int j = 0; j < 8; ++j) {
            float xv = W[(size_t)(k0 + j) * 256 + c] * 4096.0f;
            f16 hv = (f16)xv;
            hiA[j] = hv; loA[j] = (f16)(xv - (float)hv);
        }
        #pragma unroll
        for (int j = 0; j < 8; ++j) {
            float xv = W[(size_t)(k0 + 8 + j) * 256 + c] * 4096.0f;
            f16 hv = (f16)xv;
            hiB[j] = hv; loB[j] = (f16)(xv - (float)hv);
        }
        f16* pd = wthi + (size_t)c * 256 + k0;
        f16* pe = wtlo + (size_t)c * 256 + k0;
        *(f16x8*)pd = hiA; *(f16x8*)(pd + 8) = hiB;
        *(f16x8*)pe = loA; *(f16x8*)(pe + 8) = loB;
    }
}

// ---------------------------------------------------------------------------
// K1: Wh = h @ W via MFMA f16 hi/lo split (Ah*Bh + Ah*Bl + Al*Bh), fused e12.
// grid 256 blocks x 256 thr; block = 16 rows x 256 cols; wave = 16x64 (4
// 16x16 tiles). Frags loaded straight from L2, no LDS, no barriers.
// A row=lane&15, k=(lane>>4)*8+j; B col=lane&15 from Wt[col][k];
// C col=lane&15, row=(lane>>4)*4+g. Epilogue: rescale 2^-16, write Wh,
// reduce e1/e2 over the 16 col-lanes per head-half.
// ---------------------------------------------------------------------------
__global__ __launch_bounds__(256) void k_mm(const f16* __restrict__ hhi, const f16* __restrict__ hlo,
                                            const f16* __restrict__ wthi, const f16* __restrict__ wtlo,
                                            const float* __restrict__ a,
                                            float* __restrict__ Wh,
                                            float* __restrict__ e1, float* __restrict__ e2) {
    const int tid  = threadIdx.x;
    const int wv   = tid >> 6;
    const int lane = tid & 63;
    const int r    = lane & 15;
    const int q    = lane >> 4;
    const int row0 = blockIdx.x * 16;
    const int col0 = wv * 64;
    const int koff = q * 8;

    const f16* pa_hi = hhi  + (size_t)(row0 + r) * 256 + koff;
    const f16* pa_lo = hlo  + (size_t)(row0 + r) * 256 + koff;
    const f16* pb_hi = wthi + (size_t)(col0 + r) * 256 + koff;
    const f16* pb_lo = wtlo + (size_t)(col0 + r) * 256 + koff;

    f32x4 acc[4];
    #pragma unroll
    for (int t = 0; t < 4; ++t) acc[t] = (f32x4){0.f,0.f,0.f,0.f};

    struct FR { f16x8 ah, al, bh[4], bl[4]; };
    auto ldfr = [&](int ch) {
        FR f;
        const int o = ch * 32;
        f.ah = *(const f16x8*)(pa_hi + o);
        f.al = *(const f16x8*)(pa_lo + o);
        #pragma unroll
        for (int t = 0; t < 4; ++t) {
            f.bh[t] = *(const f16x8*)(pb_hi + t * (16 * 256) + o);
            f.bl[t] = *(const f16x8*)(pb_lo + t * (16 * 256) + o);
        }
        return f;
    };
    auto dom = [&](const FR& f) {
        #pragma unroll
        for (int t = 0; t < 4; ++t) {
            acc[t] = __builtin_amdgcn_mfma_f32_16x16x32_f16(f.ah, f.bh[t], acc[t], 0, 0, 0);
            acc[t] = __builtin_amdgcn_mfma_f32_16x16x32_f16(f.ah, f.bl[t], acc[t], 0, 0, 0);
            acc[t] = __builtin_amdgcn_mfma_f32_16x16x32_f16(f.al, f.bh[t], acc[t], 0, 0, 0);
        }
    };

    FR fa = ldfr(0);
    FR fb = ldfr(1);
    #pragma unroll
    for (int ch = 0; ch < 8; ch += 2) {
        dom(fa);
        if (ch + 2 < 8) fa = ldfr(ch + 2);
        dom(fb);
        if (ch + 3 < 8) fb = ldfr(ch + 3);
    }

    // undo the 2^4 * 2^12 operand scaling
    const float SC = 1.0f / 65536.0f;
    #pragma unroll
    for (int t = 0; t < 4; ++t) acc[t] *= SC;

    // Wh write (fp32)
    #pragma unroll
    for (int t = 0; t < 4; ++t)
        #pragma unroll
        for (int g = 0; g < 4; ++g)
            Wh[(size_t)(row0 + q * 4 + g) * 256 + col0 + t * 16 + r] = acc[t][g];

    // fused e1/e2: col = col0 + t*16 + r -> head = wv*2 + (t>>1), f = (t&1)*16 + r
    const float av10 = a[r], av11 = a[16 + r], av20 = a[32 + r], av21 = a[48 + r];
    float p1[8], p2[8];
    #pragma unroll
    for (int hp = 0; hp < 2; ++hp)
        #pragma unroll
        for (int g = 0; g < 4; ++g) {
            p1[hp * 4 + g] = acc[2 * hp][g] * av10 + acc[2 * hp + 1][g] * av11;
            p2[hp * 4 + g] = acc[2 * hp][g] * av20 + acc[2 * hp + 1][g] * av21;
        }
    #pragma unroll
    for (int m = 1; m < 16; m <<= 1) {
        #pragma unroll
        for (int i = 0; i < 8; ++i) {
            p1[i] += __shfl_xor(p1[i], m, 64);
            p2[i] += __shfl_xor(p2[i], m, 64);
        }
    }
    if (r == 0) {
        #pragma unroll
        for (int hp = 0; hp < 2; ++hp)
            #pragma unroll
            for (int g = 0; g < 4; ++g) {
                const int row  = row0 + q * 4 + g;
                const int b    = row >> 11;
                const int n    = row & (NTOK - 1);
                const int head = wv * 2 + hp;
                e1[(b * HEADS + head) * NTOK + n] = p1[hp * 4 + g];
                e2[(b * HEADS + head) * NTOK + n] = p2[hp * 4 + g];
            }
    }
}

// ---------------------------------------------------------------------------
// Monotone float->u32 bit map packed with (2047-j): one u64 compare gives the
// descending-with-index-tiebreak total order.
// ---------------------------------------------------------------------------
__device__ __forceinline__ unsigned long long sortkey(float f, int j) {
    unsigned int b = __float_as_uint(f);
    unsigned int u = (b & 0x80000000u) ? ~b : (b | 0x80000000u);
    return ((unsigned long long)u << 32) | (unsigned int)(NTOK - 1 - j);
}

// ---------------------------------------------------------------------------
// K3a: partial descending ranks. grid (16 bh, 8 jtile, 8 ktile), block 256.
// 1024 blocks (4/CU) — spreads the fixed 67M-compare workload so the
// LDS-broadcast read stream (128 b128/thread) stays ~10 us total.
// ---------------------------------------------------------------------------
__global__ __launch_bounds__(256) void k_rank8(const float* __restrict__ e2g,
                                               int* __restrict__ partial) {
    __shared__ alignas(16) unsigned long long ch[256];
    const int tid = threadIdx.x;
    const int bh  = blockIdx.x;
    const int jt  = blockIdx.y;
    const int kt  = blockIdx.z;
    const int kbase = kt * 256;
    ch[tid] = sortkey(e2g[bh * NTOK + kbase + tid], kbase + tid);
    __syncthreads();

    const int j = jt * 256 + tid;
    const unsigned long long my = sortkey(e2g[bh * NTOK + j], j);
    int rank = 0;
    const ulonglong2* c2 = (const ulonglong2*)ch;
    #pragma unroll 8
    for (int q = 0; q < 128; ++q) {
        ulonglong2 v = c2[q];
        rank += (v.x > my);
        rank += (v.y > my);
    }
    partial[(kt * BH + bh) * NTOK + j] = rank;
}

// ---------------------------------------------------------------------------
// K3b: sum 8 partials -> rank; scatter key/idx and exp weights.
// grid (16,8), block 256.
// ---------------------------------------------------------------------------
__global__ __launch_bounds__(256) void k_scatter(const float* __restrict__ e2g,
                                                 const int* __restrict__ partial,
                                                 float* __restrict__ skey,
                                                 int* __restrict__ sidx,
                                                 float* __restrict__ w1s,
                                                 float* __restrict__ w2s) {
    const int tid = threadIdx.x;
    const int bh  = blockIdx.x;
    const int jt  = blockIdx.y;
    const int j   = jt * 256 + tid;
    int rank = 0;
    #pragma unroll
    for (int kt = 0; kt < 8; ++kt)
        rank += partial[(kt * BH + bh) * NTOK + j];
    const float my = e2g[bh * NTOK + j];
    skey[bh * NTOK + rank] = my;
    sidx[bh * NTOK + rank] = j;
    w1s[bh * NTOK + rank]  = expf(my);
    w2s[bh * NTOK + rank]  = expf(0.01f * my);
}

// ---------------------------------------------------------------------------
// K4: work-efficient scans. grid (9 fg, 16 bh, 2 z), block 1024. (unchanged)
// ---------------------------------------------------------------------------
__global__ __launch_bounds__(1024) void k_vscan(const float* __restrict__ Wh,
                                                const int* __restrict__ sidx,
                                                const float* __restrict__ w1s,
                                                const float* __restrict__ w2s,
                                                float* __restrict__ V1,
                                                float* __restrict__ P2V,
                                                float* __restrict__ S1,
                                                float* __restrict__ P2) {
    __shared__ float4 wtot[16];
    __shared__ float4 woff[16];
    const int t    = threadIdx.x;
    const int lane = t & 63;
    const int wv   = t >> 6;
    const int fg   = blockIdx.x;
    const int bh   = blockIdx.y;
    const int z    = blockIdx.z;
    const int b    = bh >> 3;
    const int hh   = bh & 7;
    const float* wsrc = z ? w2s : w1s;

    const int j0 = 2 * t;
    float4 v0, v1;
    if (fg < 8) {
        int sj0 = sidx[bh * NTOK + j0];
        int sj1 = sidx[bh * NTOK + j0 + 1];
        float w0 = wsrc[bh * NTOK + j0];
        float w1 = wsrc[bh * NTOK + j0 + 1];
        float4 g0 = *(const float4*)(Wh + (size_t)(b * NTOK + sj0) * NCOL + hh * FOUT + fg * 4);
        float4 g1 = *(const float4*)(Wh + (size_t)(b * NTOK + sj1) * NCOL + hh * FOUT + fg * 4);
        v0 = make_float4(w0 * g0.x, w0 * g0.y, w0 * g0.z, w0 * g0.w);
        v1 = make_float4(w1 * g1.x, w1 * g1.y, w1 * g1.z, w1 * g1.w);
    } else {
        v0 = make_float4(wsrc[bh * NTOK + j0],     0.f, 0.f, 0.f);
        v1 = make_float4(wsrc[bh * NTOK + j0 + 1], 0.f, 0.f, 0.f);
    }

    float4 s = make_float4(v0.x + v1.x, v0.y + v1.y, v0.z + v1.z, v0.w + v1.w);
    #pragma unroll
    for (int d = 1; d < 64; d <<= 1) {
        float ux = __shfl_up(s.x, (unsigned)d, 64);
        float uy = __shfl_up(s.y, (unsigned)d, 64);
        float uz = __shfl_up(s.z, (unsigned)d, 64);
        float uw = __shfl_up(s.w, (unsigned)d, 64);
        if (lane >= d) { s.x += ux; s.y += uy; s.z += uz; s.w += uw; }
    }
    float4 pair = make_float4(v0.x + v1.x, v0.y + v1.y, v0.z + v1.z, v0.w + v1.w);
    float4 excl = make_float4(s.x - pair.x, s.y - pair.y, s.z - pair.z, s.w - pair.w);
    if (lane == 63) wtot[wv] = s;
    __syncthreads();
    if (t < 16) {
        float4 ws = wtot[t];
        float4 inc = ws;
        #pragma unroll
        for (int d = 1; d < 16; d <<= 1) {
            float ux = __shfl_up(inc.x, (unsigned)d, 16);
            float uy = __shfl_up(inc.y, (unsigned)d, 16);
            float uz = __shfl_up(inc.z, (unsigned)d, 16);
            float uw = __shfl_up(inc.w, (unsigned)d, 16);
            if ((t & 15) >= d) { inc.x += ux; inc.y += uy; inc.z += uz; inc.w += uw; }
        }
        woff[t] = make_float4(inc.x - ws.x, inc.y - ws.y, inc.z - ws.z, inc.w - ws.w);
    }
    __syncthreads();

    float4 base = woff[wv];
    float4 i0 = make_float4(base.x + excl.x + v0.x, base.y + excl.y + v0.y,
                            base.z + excl.z + v0.z, base.w + excl.w + v0.w);
    float4 i1 = make_float4(i0.x + v1.x, i0.y + v1.y, i0.z + v1.z, i0.w + v1.w);

    if (fg < 8) {
        float* dst = z ? P2V : V1;
        float* plane = dst + ((size_t)bh * 8 + fg) * (2049u * 4u);
        *(float4*)(plane + (size_t)(j0 + 1) * 4) = i0;
        *(float4*)(plane + (size_t)(j0 + 2) * 4) = i1;
        if (t == 0)
            *(float4*)plane = make_float4(0.f,0.f,0.f,0.f);
    } else {
        float* dst = z ? P2 : S1;
        dst[bh * 2049 + j0 + 1] = i0.x;
        dst[bh * 2049 + j0 + 2] = i1.x;
        if (t == 0) dst[bh * 2049] = 0.f;
    }
}

// ---------------------------------------------------------------------------
// K5: per (b,h,i): binary-search k_i, combine prefix sums, write output.
// grid (64 itile, 16 bh), block 256 = 32 i x 8 fg  (unchanged)
// ---------------------------------------------------------------------------
__global__ __launch_bounds__(256) void k_out(const float* __restrict__ skey,
                                             const float* __restrict__ e1g,
                                             const float* __restrict__ S1,
                                             const float* __restrict__ P2,
                                             const float* __restrict__ V1,
                                             const float* __restrict__ P2V,
                                             float* __restrict__ out) {
    __shared__ float keys[NTOK];
    const int tid = threadIdx.x;
    const int it  = blockIdx.x;
    const int bh  = blockIdx.y;
    const int b   = bh >> 3;
    const int hh  = bh & 7;
    #pragma unroll
    for (int q = 0; q < 8; ++q)
        keys[q * 256 + tid] = skey[bh * NTOK + q * 256 + tid];
    __syncthreads();

    const int i  = it * 32 + (tid >> 3);
    const int fg = tid & 7;
    const float e1v = e1g[bh * NTOK + i];
    const float th  = -e1v;
    int lo = 0, hi = NTOK;
    while (lo < hi) {
        int mid = (lo + hi) >> 1;
        if (keys[mid] > th) lo = mid + 1; else hi = mid;
    }
    const int k = lo;
    const float A = expf(e1v);
    const float C = expf(0.01f * e1v);
    const float s1  = S1[bh * 2049 + k];
    const float p2k = P2[bh * 2049 + k];
    const float p2t = P2[bh * 2049 + 2048];
    const float l   = A * s1 + C * (p2t - p2k);
    const float inv = 1.0f / l;
    const float* v1p  = V1  + ((size_t)bh * 8 + fg) * (2049u * 4u);
    const float* p2vp = P2V + ((size_t)bh * 8 + fg) * (2049u * 4u);
    float4 v1   = *(const float4*)(v1p  + (size_t)k * 4);
    float4 p2v  = *(const float4*)(p2vp + (size_t)k * 4);
    float4 p2vt = *(const float4*)(p2vp + (size_t)2048 * 4);
    float4 o;
    o.x = (A * v1.x + C * (p2vt.x - p2v.x)) * inv;
    o.y = (A * v1.y + C * (p2vt.y - p2v.y)) * inv;
    o.z = (A * v1.z + C * (p2vt.z - p2v.z)) * inv;
    o.w = (A * v1.w + C * (p2vt.w - p2v.w)) * inv;
    *(float4*)(out + (size_t)(b * NTOK + i) * NCOL + hh * FOUT + fg * 4) = o;
}

// ---------------------------------------------------------------------------
extern "C" void kernel_launch(void* const* d_in, const int* in_sizes, int n_in,
                              void* d_out, int out_size, void* d_ws, size_t ws_size,
                              hipStream_t stream) {
    const float* h = (const float*)d_in[0];
    // d_in[1] = adj — unused by the reference computation
    const float* W = (const float*)d_in[2];
    const float* a = (const float*)d_in[3];
    float* out = (float*)d_out;
    float* ws  = (float*)d_ws;

    float* Wh   = ws;
    float* e1   = ws + OFF_E1;
    float* e2   = ws + OFF_E2;
    float* skey = ws + OFF_SKEY;
    int*   sidx = (int*)(ws + OFF_SIDX);
    float* w1s  = ws + OFF_W1S;
    float* w2s  = ws + OFF_W2S;
    float* S1   = ws + OFF_S1;
    float* P2   = ws + OFF_P2;
    float* V1   = ws + OFF_V1;
    float* P2V  = ws + OFF_P2V;
    f16*   hhi  = (f16*)(ws + OFF_HHI);
    f16*   hlo  = (f16*)(ws + OFF_HLO);
    f16*   wthi = (f16*)(ws + OFF_WTHI);
    f16*   wtlo = (f16*)(ws + OFF_WTLO);
    int*   part = (int*)(ws + OFF_PART);   // aliases V1 (safe: consumed before vscan)

    k_split  <<<528,              256, 0, stream>>>(h, W, hhi, hlo, wthi, wtlo);
    k_mm     <<<256,              256, 0, stream>>>(hhi, hlo, wthi, wtlo, a, Wh, e1, e2);
    k_rank8  <<<dim3(BH, 8, 8),   256, 0, stream>>>(e2, part);
    k_scatter<<<dim3(BH, 8),      256, 0, stream>>>(e2, part, skey, sidx, w1s, w2s);
    k_vscan  <<<dim3(9, BH, 2),  1024, 0, stream>>>(Wh, sidx, w1s, w2s, V1, P2V, S1, P2);
    k_out    <<<dim3(NTOK/32, BH),256, 0, stream>>>(skey, e1, S1, P2, V1, P2V, out);
}

// Round 5
// 116.913 us; speedup vs baseline: 1.1205x; 1.0617x over previous
//
#include <hip/hip_runtime.h>
#include <math.h>

// Problem constants
#define BATCH 2
#define NTOK  2048
#define FIN   256
#define HEADS 8
#define FOUT  32
#define BH    (BATCH*HEADS)    // 16
#define NCOL  (HEADS*FOUT)     // 256
#define ROWS  (BATCH*NTOK)     // 4096

typedef _Float16 f16;
typedef _Float16 f16x8 __attribute__((ext_vector_type(8)));
typedef float    f32x4 __attribute__((ext_vector_type(4)));

// ---------------------------------------------------------------------------
// Workspace layout (float offsets).
// V1/P2V fg-plane-major [bh][fg][2049][4]. partial ranks alias V1 (rank8
// writes partial -> scatter reads -> vscan overwrites V1 later; strict
// stream order makes the aliasing safe). No more f16 staging buffers:
// the hi/lo split now happens in-register inside k_mm.
// ---------------------------------------------------------------------------
static const size_t OFF_E1   = 1048576;                 // e1  [16][2048]
static const size_t OFF_E2   = OFF_E1 + 32768;          // e2  [16][2048]
static const size_t OFF_SKEY = OFF_E2 + 32768;          // skey[16][2048]
static const size_t OFF_SIDX = OFF_SKEY + 32768;        // sidx[16][2048] int
static const size_t OFF_W1S  = OFF_SIDX + 32768;        // w1s [16][2048]
static const size_t OFF_W2S  = OFF_W1S + 32768;         // w2s [16][2048]
static const size_t OFF_S1   = OFF_W2S + 32768;         // S1  [16][2049]
static const size_t OFF_P2   = OFF_S1 + 32784;          // P2  [16][2049]
static const size_t OFF_V1   = OFF_P2 + 32784;          // V1  [16][8][2049][4]
static const size_t OFF_P2V  = OFF_V1 + 16u*2049u*32u;  // P2V [16][8][2049][4]
static const size_t OFF_PART = OFF_V1;                  // partial[8][16][2048] int (aliases V1)

// ---------------------------------------------------------------------------
// K1: Wh = h @ W via MFMA f16 hi/lo split (Ah*Bh + Ah*Bl + Al*Bh), with the
// fp32->f16 split done IN-REGISTER (k_split kernel eliminated).
// grid 256 blocks x 512 thr. Block = 16 rows x 256 cols; wave w = head w
// (16 rows x 32 cols = 2 MFMA col-tiles) -> 8 waves/CU = 2/SIMD TLP.
// A: lane(r,q) loads h[row0+r][k..k+8) fp32 (2 float4, 64B/row across q).
// B: 8 scalar fp32 loads per tile: lanes span 16 consecutive cols x 4 k-rows
//    = 4 full 64B sectors per instruction; W is L2-resident (64 MB aggregate).
// Scaling h*2^4, W*2^12 keeps lo-residuals f16-normal; epilogue *2^-16.
// Frag layout (R4-validated): A row=lane&15, k=(lane>>4)*8+j; B col likewise
// from W[k][col]; C col=lane&15, row=(lane>>4)*4+g.
// Epilogue: write Wh fp32, reduce e1/e2 over the 16 r-lanes (head = wave).
// ---------------------------------------------------------------------------
__global__ __launch_bounds__(512) void k_mm(const float* __restrict__ h,
                                            const float* __restrict__ W,
                                            const float* __restrict__ av,
                                            float* __restrict__ Wh,
                                            float* __restrict__ e1, float* __restrict__ e2) {
    const int tid  = threadIdx.x;
    const int hh   = tid >> 6;        // wave index == head
    const int lane = tid & 63;
    const int r    = lane & 15;
    const int q    = lane >> 4;
    const int row0 = blockIdx.x * 16;
    const int colA = hh * 32;

    const float* pa = h + (size_t)(row0 + r) * FIN + q * 8;
    const float HS = 16.0f, WS = 4096.0f;

    f32x4 acc[2];
    acc[0] = (f32x4){0.f,0.f,0.f,0.f};
    acc[1] = (f32x4){0.f,0.f,0.f,0.f};

    for (int ks = 0; ks < 8; ++ks) {
        const int kb = ks * 32;
        // ---- A split in-register ----
        const float4 a0 = *(const float4*)(pa + kb);
        const float4 a1 = *(const float4*)(pa + kb + 4);
        const float ax[8] = {a0.x,a0.y,a0.z,a0.w,a1.x,a1.y,a1.z,a1.w};
        f16x8 ahi, alo;
        #pragma unroll
        for (int j = 0; j < 8; ++j) {
            float xv = ax[j] * HS;
            f16 hv = (f16)xv;
            ahi[j] = hv; alo[j] = (f16)(xv - (float)hv);
        }
        // ---- B split in-register, 2 col-tiles ----
        f16x8 bhi[2], blo[2];
        #pragma unroll
        for (int t = 0; t < 2; ++t) {
            const float* pb = W + (size_t)(kb + q * 8) * NCOL + colA + t * 16 + r;
            #pragma unroll
            for (int j = 0; j < 8; ++j) {
                float xv = pb[(size_t)j * NCOL] * WS;
                f16 hv = (f16)xv;
                bhi[t][j] = hv; blo[t][j] = (f16)(xv - (float)hv);
            }
        }
        #pragma unroll
        for (int t = 0; t < 2; ++t) {
            acc[t] = __builtin_amdgcn_mfma_f32_16x16x32_f16(ahi, bhi[t], acc[t], 0, 0, 0);
            acc[t] = __builtin_amdgcn_mfma_f32_16x16x32_f16(ahi, blo[t], acc[t], 0, 0, 0);
            acc[t] = __builtin_amdgcn_mfma_f32_16x16x32_f16(alo, bhi[t], acc[t], 0, 0, 0);
        }
    }

    const float SC = 1.0f / 65536.0f;   // undo 2^4 * 2^12
    acc[0] *= SC; acc[1] *= SC;

    // Wh write (fp32)
    #pragma unroll
    for (int t = 0; t < 2; ++t)
        #pragma unroll
        for (int g = 0; g < 4; ++g)
            Wh[(size_t)(row0 + q * 4 + g) * NCOL + colA + t * 16 + r] = acc[t][g];

    // fused e1/e2: wave == head; f = t*16 + r
    const float a10 = av[r], a11 = av[16 + r];
    const float a20 = av[32 + r], a21 = av[48 + r];
    float p1[4], p2[4];
    #pragma unroll
    for (int g = 0; g < 4; ++g) {
        p1[g] = acc[0][g] * a10 + acc[1][g] * a11;
        p2[g] = acc[0][g] * a20 + acc[1][g] * a21;
    }
    #pragma unroll
    for (int m = 1; m < 16; m <<= 1)
        #pragma unroll
        for (int g = 0; g < 4; ++g) {
            p1[g] += __shfl_xor(p1[g], m, 64);
            p2[g] += __shfl_xor(p2[g], m, 64);
        }
    if (r == 0) {
        #pragma unroll
        for (int g = 0; g < 4; ++g) {
            const int row = row0 + q * 4 + g;
            const int b   = row >> 11;
            const int n   = row & (NTOK - 1);
            e1[(b * HEADS + hh) * NTOK + n] = p1[g];
            e2[(b * HEADS + hh) * NTOK + n] = p2[g];
        }
    }
}

// ---------------------------------------------------------------------------
// Monotone float->u32 bit map packed with (2047-j): one u64 compare gives the
// descending-with-index-tiebreak total order.
// ---------------------------------------------------------------------------
__device__ __forceinline__ unsigned long long sortkey(float f, int j) {
    unsigned int b = __float_as_uint(f);
    unsigned int u = (b & 0x80000000u) ? ~b : (b | 0x80000000u);
    return ((unsigned long long)u << 32) | (unsigned int)(NTOK - 1 - j);
}

// ---------------------------------------------------------------------------
// K3a: partial descending ranks, 4-j amortized. grid (16 bh, 8 kt, 2 jh),
// block 256 -> 256 blocks (1/CU). Each thread ranks FOUR j's against the
// staged 256-key chunk: LDS-issue count per CU drops 4x vs 1-j version
// (24.6k -> 6.1k cyc), now balanced against the u64-compare VALU stream.
// ---------------------------------------------------------------------------
__global__ __launch_bounds__(256) void k_rank8(const float* __restrict__ e2g,
                                               int* __restrict__ partial) {
    __shared__ alignas(16) unsigned long long ch[256];
    const int tid = threadIdx.x;
    const int bh  = blockIdx.x;
    const int kt  = blockIdx.y;
    const int jh  = blockIdx.z;
    const int kbase = kt * 256;
    ch[tid] = sortkey(e2g[bh * NTOK + kbase + tid], kbase + tid);
    __syncthreads();

    const int j0 = jh * 1024 + tid * 4;
    const float4 mv = *(const float4*)(e2g + bh * NTOK + j0);
    const unsigned long long my0 = sortkey(mv.x, j0);
    const unsigned long long my1 = sortkey(mv.y, j0 + 1);
    const unsigned long long my2 = sortkey(mv.z, j0 + 2);
    const unsigned long long my3 = sortkey(mv.w, j0 + 3);
    int r0 = 0, r1 = 0, r2 = 0, r3 = 0;
    const ulonglong2* c2 = (const ulonglong2*)ch;
    #pragma unroll 8
    for (int qq = 0; qq < 128; ++qq) {
        ulonglong2 v = c2[qq];
        r0 += (v.x > my0) + (v.y > my0);
        r1 += (v.x > my1) + (v.y > my1);
        r2 += (v.x > my2) + (v.y > my2);
        r3 += (v.x > my3) + (v.y > my3);
    }
    *(int4*)(partial + (size_t)(kt * BH + bh) * NTOK + j0) = make_int4(r0, r1, r2, r3);
}

// ---------------------------------------------------------------------------
// K3b: sum 8 partials -> rank; scatter key/idx and exp weights.
// grid (16,8), block 256.
// ---------------------------------------------------------------------------
__global__ __launch_bounds__(256) void k_scatter(const float* __restrict__ e2g,
                                                 const int* __restrict__ partial,
                                                 float* __restrict__ skey,
                                                 int* __restrict__ sidx,
                                                 float* __restrict__ w1s,
                                                 float* __restrict__ w2s) {
    const int tid = threadIdx.x;
    const int bh  = blockIdx.x;
    const int jt  = blockIdx.y;
    const int j   = jt * 256 + tid;
    int rank = 0;
    #pragma unroll
    for (int kt = 0; kt < 8; ++kt)
        rank += partial[(size_t)(kt * BH + bh) * NTOK + j];
    const float my = e2g[bh * NTOK + j];
    skey[bh * NTOK + rank] = my;
    sidx[bh * NTOK + rank] = j;
    w1s[bh * NTOK + rank]  = expf(my);
    w2s[bh * NTOK + rank]  = expf(0.01f * my);
}

// ---------------------------------------------------------------------------
// K4: work-efficient scans, z-FUSED. grid (9 fg, 16 bh), block 1024.
// The Wh gather (the expensive random part) happens ONCE; both z=0 (w1)
// and z=1 (w2) scans run from registers. 144 blocks (no 2-block/CU tail).
// fg==8 handled by the same float4 path via g=(1,0,0,0).
// Writes exclusive form dst[k]=incl[k-1], dst[0]=0, dst[2048]=total.
// ---------------------------------------------------------------------------
__global__ __launch_bounds__(1024) void k_vscan(const float* __restrict__ Wh,
                                                const int* __restrict__ sidx,
                                                const float* __restrict__ w1s,
                                                const float* __restrict__ w2s,
                                                float* __restrict__ V1,
                                                float* __restrict__ P2V,
                                                float* __restrict__ S1,
                                                float* __restrict__ P2) {
    __shared__ float4 wtot[16];
    __shared__ float4 woff[16];
    const int t    = threadIdx.x;
    const int lane = t & 63;
    const int wv   = t >> 6;
    const int fg   = blockIdx.x;
    const int bh   = blockIdx.y;
    const int b    = bh >> 3;
    const int hh   = bh & 7;
    const int j0   = 2 * t;

    const float w1_0 = w1s[bh * NTOK + j0], w1_1 = w1s[bh * NTOK + j0 + 1];
    const float w2_0 = w2s[bh * NTOK + j0], w2_1 = w2s[bh * NTOK + j0 + 1];
    float4 g0, g1;
    if (fg < 8) {
        const int sj0 = sidx[bh * NTOK + j0];
        const int sj1 = sidx[bh * NTOK + j0 + 1];
        g0 = *(const float4*)(Wh + (size_t)(b * NTOK + sj0) * NCOL + hh * FOUT + fg * 4);
        g1 = *(const float4*)(Wh + (size_t)(b * NTOK + sj1) * NCOL + hh * FOUT + fg * 4);
    } else {
        g0 = make_float4(1.f, 0.f, 0.f, 0.f);
        g1 = make_float4(1.f, 0.f, 0.f, 0.f);
    }

    #pragma unroll 1
    for (int z = 0; z < 2; ++z) {
        const float w0  = z ? w2_0 : w1_0;
        const float w1v = z ? w2_1 : w1_1;
        float4 v0 = make_float4(w0 * g0.x,  w0 * g0.y,  w0 * g0.z,  w0 * g0.w);
        float4 v1 = make_float4(w1v * g1.x, w1v * g1.y, w1v * g1.z, w1v * g1.w);

        // thread-local pair sum, then inclusive wave scan
        float4 s = make_float4(v0.x + v1.x, v0.y + v1.y, v0.z + v1.z, v0.w + v1.w);
        #pragma unroll
        for (int d = 1; d < 64; d <<= 1) {
            float ux = __shfl_up(s.x, (unsigned)d, 64);
            float uy = __shfl_up(s.y, (unsigned)d, 64);
            float uz = __shfl_up(s.z, (unsigned)d, 64);
            float uw = __shfl_up(s.w, (unsigned)d, 64);
            if (lane >= d) { s.x += ux; s.y += uy; s.z += uz; s.w += uw; }
        }
        float4 pair = make_float4(v0.x + v1.x, v0.y + v1.y, v0.z + v1.z, v0.w + v1.w);
        float4 excl = make_float4(s.x - pair.x, s.y - pair.y, s.z - pair.z, s.w - pair.w);
        if (lane == 63) wtot[wv] = s;
        __syncthreads();
        if (t < 16) {
            float4 ws = wtot[t];
            float4 inc = ws;
            #pragma unroll
            for (int d = 1; d < 16; d <<= 1) {
                float ux = __shfl_up(inc.x, (unsigned)d, 16);
                float uy = __shfl_up(inc.y, (unsigned)d, 16);
                float uz = __shfl_up(inc.z, (unsigned)d, 16);
                float uw = __shfl_up(inc.w, (unsigned)d, 16);
                if ((t & 15) >= d) { inc.x += ux; inc.y += uy; inc.z += uz; inc.w += uw; }
            }
            woff[t] = make_float4(inc.x - ws.x, inc.y - ws.y, inc.z - ws.z, inc.w - ws.w);
        }
        __syncthreads();

        float4 base = woff[wv];
        float4 i0 = make_float4(base.x + excl.x + v0.x, base.y + excl.y + v0.y,
                                base.z + excl.z + v0.z, base.w + excl.w + v0.w);
        float4 i1 = make_float4(i0.x + v1.x, i0.y + v1.y, i0.z + v1.z, i0.w + v1.w);

        if (fg < 8) {
            float* dst = z ? P2V : V1;
            float* plane = dst + ((size_t)bh * 8 + fg) * (2049u * 4u);
            *(float4*)(plane + (size_t)(j0 + 1) * 4) = i0;
            *(float4*)(plane + (size_t)(j0 + 2) * 4) = i1;
            if (t == 0)
                *(float4*)plane = make_float4(0.f, 0.f, 0.f, 0.f);
        } else {
            float* dst = z ? P2 : S1;
            dst[bh * 2049 + j0 + 1] = i0.x;
            dst[bh * 2049 + j0 + 2] = i1.x;
            if (t == 0) dst[bh * 2049] = 0.f;
        }
        __syncthreads();   // protect wtot/woff reuse by the next z pass
    }
}

// ---------------------------------------------------------------------------
// K5: per (b,h,i): binary-search k_i, combine prefix sums, write output.
// grid (64 itile, 16 bh), block 256 = 32 i x 8 fg  (unchanged)
// ---------------------------------------------------------------------------
__global__ __launch_bounds__(256) void k_out(const float* __restrict__ skey,
                                             const float* __restrict__ e1g,
                                             const float* __restrict__ S1,
                                             const float* __restrict__ P2,
                                             const float* __restrict__ V1,
                                             const float* __restrict__ P2V,
                                             float* __restrict__ out) {
    __shared__ float keys[NTOK];
    const int tid = threadIdx.x;
    const int it  = blockIdx.x;
    const int bh  = blockIdx.y;
    const int b   = bh >> 3;
    const int hh  = bh & 7;
    #pragma unroll
    for (int q = 0; q < 8; ++q)
        keys[q * 256 + tid] = skey[bh * NTOK + q * 256 + tid];
    __syncthreads();

    const int i  = it * 32 + (tid >> 3);
    const int fg = tid & 7;
    const float e1v = e1g[bh * NTOK + i];
    const float th  = -e1v;
    int lo = 0, hi = NTOK;
    while (lo < hi) {
        int mid = (lo + hi) >> 1;
        if (keys[mid] > th) lo = mid + 1; else hi = mid;
    }
    const int k = lo;
    const float A = expf(e1v);
    const float C = expf(0.01f * e1v);
    const float s1  = S1[bh * 2049 + k];
    const float p2k = P2[bh * 2049 + k];
    const float p2t = P2[bh * 2049 + 2048];
    const float l   = A * s1 + C * (p2t - p2k);
    const float inv = 1.0f / l;
    const float* v1p  = V1  + ((size_t)bh * 8 + fg) * (2049u * 4u);
    const float* p2vp = P2V + ((size_t)bh * 8 + fg) * (2049u * 4u);
    float4 v1   = *(const float4*)(v1p  + (size_t)k * 4);
    float4 p2v  = *(const float4*)(p2vp + (size_t)k * 4);
    float4 p2vt = *(const float4*)(p2vp + (size_t)2048 * 4);
    float4 o;
    o.x = (A * v1.x + C * (p2vt.x - p2v.x)) * inv;
    o.y = (A * v1.y + C * (p2vt.y - p2v.y)) * inv;
    o.z = (A * v1.z + C * (p2vt.z - p2v.z)) * inv;
    o.w = (A * v1.w + C * (p2vt.w - p2v.w)) * inv;
    *(float4*)(out + (size_t)(b * NTOK + i) * NCOL + hh * FOUT + fg * 4) = o;
}

// ---------------------------------------------------------------------------
extern "C" void kernel_launch(void* const* d_in, const int* in_sizes, int n_in,
                              void* d_out, int out_size, void* d_ws, size_t ws_size,
                              hipStream_t stream) {
    const float* h = (const float*)d_in[0];
    // d_in[1] = adj — unused by the reference computation
    const float* W = (const float*)d_in[2];
    const float* a = (const float*)d_in[3];
    float* out = (float*)d_out;
    float* ws  = (float*)d_ws;

    float* Wh   = ws;
    float* e1   = ws + OFF_E1;
    float* e2   = ws + OFF_E2;
    float* skey = ws + OFF_SKEY;
    int*   sidx = (int*)(ws + OFF_SIDX);
    float* w1s  = ws + OFF_W1S;
    float* w2s  = ws + OFF_W2S;
    float* S1   = ws + OFF_S1;
    float* P2   = ws + OFF_P2;
    float* V1   = ws + OFF_V1;
    float* P2V  = ws + OFF_P2V;
    int*   part = (int*)(ws + OFF_PART);   // aliases V1 (safe: consumed before vscan)

    k_mm     <<<256,               512, 0, stream>>>(h, W, a, Wh, e1, e2);
    k_rank8  <<<dim3(BH, 8, 2),    256, 0, stream>>>(e2, part);
    k_scatter<<<dim3(BH, 8),       256, 0, stream>>>(e2, part, skey, sidx, w1s, w2s);
    k_vscan  <<<dim3(9, BH),      1024, 0, stream>>>(Wh, sidx, w1s, w2s, V1, P2V, S1, P2);
    k_out    <<<dim3(NTOK/32, BH), 256, 0, stream>>>(skey, e1, S1, P2, V1, P2V, out);
}